// Round 1
// baseline (59.269 us; speedup 1.0000x reference)
//
#include <hip/hip_runtime.h>
#include <stdint.h>

#define N_OUT    4096
#define N_IN     4096
#define TOKENS   256
#define N_SPARSE 8388608
#define SPLITK   8
#define KCHUNK   (N_IN / SPLITK)   // 512
#define BM       128
#define BN       128
#define BK       32

typedef __attribute__((ext_vector_type(8))) short bf16x8;
typedef __attribute__((ext_vector_type(4))) float f32x4;

__device__ __forceinline__ unsigned short f2bf(float f) {
    union { float f; unsigned u; } v; v.f = f;
    unsigned r = v.u + 0x7fffu + ((v.u >> 16) & 1u);   // RNE
    return (unsigned short)(r >> 16);
}

__device__ __forceinline__ void gload_lds16(const void* g, void* l) {
    __builtin_amdgcn_global_load_lds(
        (const __attribute__((address_space(1))) void*)g,
        (__attribute__((address_space(3))) void*)l, 16, 0, 0);
}

// ---- kernel 1: x (fp32) -> xb (bf16) -------------------------------------
__global__ void convert_x(const float* __restrict__ x, unsigned short* __restrict__ xb) {
    int i = (blockIdx.x * 256 + threadIdx.x) * 4;
    const float4 v = *(const float4*)(x + i);
    ushort4 o;
    o.x = f2bf(v.x); o.y = f2bf(v.y); o.z = f2bf(v.z); o.w = f2bf(v.w);
    *(ushort4*)(xb + i) = o;
}

// ---- kernel 2: scatter sparse values into dense bf16 W -------------------
__global__ void scatter_w(const int* __restrict__ idx, const float* __restrict__ vals,
                          unsigned short* __restrict__ wb) {
    int k = blockIdx.x * 256 + threadIdx.x;
    wb[idx[k]] = f2bf(vals[k]);
}

// ---- kernel 3: bf16 MFMA GEMM, A (M x K) row-major, B (N x K) row-major --
// out-partial[z][m][n] = sum_{k in chunk z} A[m][k]*B[n][k]
__global__ __launch_bounds__(256) void gemm_bt_splitk(
        const unsigned short* __restrict__ xb,   // 256 x 4096 bf16
        const unsigned short* __restrict__ wb,   // 4096 x 4096 bf16
        float* __restrict__ part)                // SPLITK x 256 x 4096 f32
{
    __shared__ short As[BM * BK];
    __shared__ short Bs[BN * BK];

    const int tid = threadIdx.x;
    const int l   = tid & 63;
    const int w   = tid >> 6;
    const int bn  = blockIdx.x;
    const int bm  = blockIdx.y;
    const int bz  = blockIdx.z;

    const size_t k0 = (size_t)bz * KCHUNK;
    const unsigned short* ag = xb + (size_t)(bm * BM) * N_IN + k0;
    const unsigned short* bg = wb + (size_t)(bn * BN) * N_IN + k0;

    const int srow = l >> 2;          // row within 16-row stripe
    const int scol = (l & 3) * 8;     // 8 bf16 = 16B per lane

    const int mbase = (w >> 1) * 64;
    const int nbase = (w & 1) * 64;
    const int lr = l & 15;
    const int kg = (l >> 4) * 8;

    f32x4 acc[4][4] = {};

    for (int kt = 0; kt < KCHUNK; kt += BK) {
        // stage A and B tiles: per wave, 2 stripes of 16 rows each (1KB per issue)
        #pragma unroll
        for (int q = 0; q < 2; ++q) {
            const int rbase = (q * 4 + w) * 16;
            gload_lds16(ag + (size_t)(rbase + srow) * N_IN + kt + scol, &As[rbase * BK]);
            gload_lds16(bg + (size_t)(rbase + srow) * N_IN + kt + scol, &Bs[rbase * BK]);
        }
        __syncthreads();   // drains vmcnt(0): LDS tiles ready

        bf16x8 af[4], bfr[4];
        #pragma unroll
        for (int i = 0; i < 4; ++i)
            af[i] = *(const bf16x8*)&As[(mbase + i * 16 + lr) * BK + kg];
        #pragma unroll
        for (int i = 0; i < 4; ++i)
            bfr[i] = *(const bf16x8*)&Bs[(nbase + i * 16 + lr) * BK + kg];

        #pragma unroll
        for (int mi = 0; mi < 4; ++mi)
            #pragma unroll
            for (int ni = 0; ni < 4; ++ni)
                acc[mi][ni] = __builtin_amdgcn_mfma_f32_16x16x32_bf16(
                                  af[mi], bfr[ni], acc[mi][ni], 0, 0, 0);

        __syncthreads();   // everyone done reading before next stage
    }

    // epilogue: C/D layout col = lane&15, row = (lane>>4)*4 + reg
    float* po = part + (size_t)bz * (TOKENS * N_OUT)
                     + (size_t)(bm * BM + mbase) * N_OUT + bn * BN + nbase;
    const int rq = (l >> 4) * 4;
    #pragma unroll
    for (int mi = 0; mi < 4; ++mi)
        #pragma unroll
        for (int r = 0; r < 4; ++r) {
            const int row = mi * 16 + rq + r;
            #pragma unroll
            for (int ni = 0; ni < 4; ++ni)
                po[(size_t)row * N_OUT + ni * 16 + lr] = acc[mi][ni][r];
        }
}

// ---- kernel 4: sum split-K partials --------------------------------------
__global__ void reduce_k(const float* __restrict__ part, float* __restrict__ out) {
    int i = (blockIdx.x * 256 + threadIdx.x) * 4;
    float4 a = *(const float4*)(part + i);
    #pragma unroll
    for (int z = 1; z < SPLITK; ++z) {
        float4 b = *(const float4*)(part + (size_t)z * (TOKENS * N_OUT) + i);
        a.x += b.x; a.y += b.y; a.z += b.z; a.w += b.w;
    }
    *(float4*)(out + i) = a;
}

// ---- fallback (ws too small): per-output-row CSR, fp32 -------------------
__global__ void fallback_rowcsr(const float* __restrict__ x, const float* __restrict__ vals,
                                const int* __restrict__ idx, float* __restrict__ out) {
    const int o = blockIdx.x;
    const int t = threadIdx.x;
    __shared__ int   scol[256];
    __shared__ float sval[256];

    int lo = 0, hi = N_SPARSE;
    const int target = o * N_IN;
    while (lo < hi) { int m = (lo + hi) >> 1; if (idx[m] < target) lo = m + 1; else hi = m; }
    const int start = lo;
    hi = N_SPARSE;
    const int target2 = target + N_IN;
    while (lo < hi) { int m = (lo + hi) >> 1; if (idx[m] < target2) lo = m + 1; else hi = m; }
    const int end = lo;

    float acc = 0.f;
    const float* xr = x + (size_t)t * N_IN;
    for (int base = start; base < end; base += 256) {
        const int k = base + t;
        if (k < end) { scol[t] = idx[k] - target; sval[t] = vals[k]; }
        __syncthreads();
        const int cnt = min(256, end - base);
        for (int j = 0; j < cnt; ++j) acc += sval[j] * xr[scol[j]];
        __syncthreads();
    }
    out[(size_t)t * N_OUT + o] = acc;
}

extern "C" void kernel_launch(void* const* d_in, const int* in_sizes, int n_in,
                              void* d_out, int out_size, void* d_ws, size_t ws_size,
                              hipStream_t stream) {
    const float* x    = (const float*)d_in[0];
    const float* vals = (const float*)d_in[1];
    const int*   idx  = (const int*)d_in[2];
    float* out = (float*)d_out;

    const size_t wb_bytes   = (size_t)N_OUT * N_IN * 2;              // 32 MB
    const size_t xb_bytes   = (size_t)TOKENS * N_IN * 2;             // 2 MB
    const size_t part_bytes = (size_t)SPLITK * TOKENS * N_OUT * 4;   // 32 MB
    const size_t need = wb_bytes + xb_bytes + part_bytes;            // ~66 MB

    if (ws_size >= need) {
        unsigned short* wb = (unsigned short*)d_ws;
        unsigned short* xb = (unsigned short*)((char*)d_ws + wb_bytes);
        float* part        = (float*)((char*)d_ws + wb_bytes + xb_bytes);

        hipMemsetAsync(wb, 0, wb_bytes, stream);
        convert_x<<<(TOKENS * N_IN) / 1024, 256, 0, stream>>>(x, xb);
        scatter_w<<<N_SPARSE / 256, 256, 0, stream>>>(idx, vals, wb);
        dim3 grid(N_OUT / BN, TOKENS / BM, SPLITK);
        gemm_bt_splitk<<<grid, 256, 0, stream>>>(xb, wb, part);
        reduce_k<<<(TOKENS * N_OUT) / 1024, 256, 0, stream>>>(part, out);
    } else {
        fallback_rowcsr<<<N_OUT, TOKENS, 0, stream>>>(x, vals, idx, out);
    }
}